// Round 3
// baseline (237.364 us; speedup 1.0000x reference)
//
#include <hip/hip_runtime.h>
#include <math.h>

#define REGION_MAX 116
#define EMB 768
#define DIM_D 182
#define DIM_H 218
#define DIM_W 182

typedef float v4f __attribute__((ext_vector_type(4)));

// --- setup: M = inv(aal_affine) @ mri_affine, store top 3 rows (12 floats) ---
__global__ void compute_M_kernel(const float* __restrict__ mri,
                                 const float* __restrict__ aal,
                                 float* __restrict__ M) {
    if (threadIdx.x != 0 || blockIdx.x != 0) return;
    float a[4][8];
    for (int i = 0; i < 4; ++i)
        for (int j = 0; j < 4; ++j) {
            a[i][j]     = aal[i * 4 + j];
            a[i][j + 4] = (i == j) ? 1.0f : 0.0f;
        }
    // Gauss-Jordan with partial pivoting
    for (int c = 0; c < 4; ++c) {
        int piv = c;
        float best = fabsf(a[c][c]);
        for (int r = c + 1; r < 4; ++r) {
            float v = fabsf(a[r][c]);
            if (v > best) { best = v; piv = r; }
        }
        if (piv != c)
            for (int j = 0; j < 8; ++j) {
                float t = a[c][j]; a[c][j] = a[piv][j]; a[piv][j] = t;
            }
        float inv = 1.0f / a[c][c];
        for (int j = 0; j < 8; ++j) a[c][j] *= inv;
        for (int r = 0; r < 4; ++r) {
            if (r == c) continue;
            float f = a[r][c];
            for (int j = 0; j < 8; ++j) a[r][j] -= f * a[c][j];
        }
    }
    // M = inv(aal) @ mri  (rows 0..2 only)
    for (int i = 0; i < 3; ++i)
        for (int j = 0; j < 4; ++j) {
            float s = 0.0f;
            for (int k = 0; k < 4; ++k) s += a[i][4 + k] * mri[k * 4 + j];
            M[i * 4 + j] = s;
        }
}

__device__ __forceinline__ int region_of(const float* __restrict__ centers,
                                         const float* __restrict__ M,
                                         const float* __restrict__ vol,
                                         int p) {
    float px = centers[p * 3 + 0];
    float py = centers[p * 3 + 1];
    float pz = centers[p * 3 + 2];

    float fx = M[0] * px + M[1] * py + M[2]  * pz + M[3];
    float fy = M[4] * px + M[5] * py + M[6]  * pz + M[7];
    float fz = M[8] * px + M[9] * py + M[10] * pz + M[11];

    int x = (int)rintf(fx);   // round half-to-even, matches jnp.round
    int y = (int)rintf(fy);
    int z = (int)rintf(fz);

    bool inb = (x >= 0) & (x < DIM_D) & (y >= 0) & (y < DIM_H) &
               (z >= 0) & (z < DIM_W);
    int cx = min(max(x, 0), DIM_D - 1);
    int cy = min(max(y, 0), DIM_H - 1);
    int cz = min(max(z, 0), DIM_W - 1);

    int region = (int)vol[((size_t)cx * DIM_H + cy) * DIM_W + cz];  // trunc = astype(int32)
    return (inb && region >= 0 && region <= REGION_MAX) ? region : 0;
}

// --- main: one wave per 2 points; 6 independent float4 copy streams/lane ---
__global__ __launch_bounds__(256) void aal_embed_kernel(
    const float* __restrict__ centers,   // [P,3]
    const float* __restrict__ M,         // 12 floats
    const float* __restrict__ vol,       // [D,H,W]
    const float* __restrict__ table,     // [117, EMB]
    float* __restrict__ out,             // [P, EMB]
    int P) {
    int wave = blockIdx.x * (blockDim.x >> 6) + (threadIdx.x >> 6);
    // force scalar (SGPR) addressing for the wave-uniform point loads
    wave = __builtin_amdgcn_readfirstlane(wave);
    int lane = threadIdx.x & 63;

    int p0 = wave * 2;
    int p1 = p0 + 1;
    if (p0 >= P) return;

    int rid0 = region_of(centers, M, vol, p0);
    const v4f* __restrict__ s0 = (const v4f*)(table + (size_t)rid0 * EMB);
    v4f* __restrict__ d0 = (v4f*)(out + (size_t)p0 * EMB);

    if (p1 < P) {
        int rid1 = region_of(centers, M, vol, p1);
        const v4f* __restrict__ s1 = (const v4f*)(table + (size_t)rid1 * EMB);
        v4f* __restrict__ d1 = (v4f*)(out + (size_t)p1 * EMB);

        // issue all 6 loads, then all 6 streaming stores
        v4f a0 = s0[lane], a1 = s0[lane + 64], a2 = s0[lane + 128];
        v4f b0 = s1[lane], b1 = s1[lane + 64], b2 = s1[lane + 128];
        __builtin_nontemporal_store(a0, &d0[lane]);
        __builtin_nontemporal_store(a1, &d0[lane + 64]);
        __builtin_nontemporal_store(a2, &d0[lane + 128]);
        __builtin_nontemporal_store(b0, &d1[lane]);
        __builtin_nontemporal_store(b1, &d1[lane + 64]);
        __builtin_nontemporal_store(b2, &d1[lane + 128]);
    } else {
        v4f a0 = s0[lane], a1 = s0[lane + 64], a2 = s0[lane + 128];
        __builtin_nontemporal_store(a0, &d0[lane]);
        __builtin_nontemporal_store(a1, &d0[lane + 64]);
        __builtin_nontemporal_store(a2, &d0[lane + 128]);
    }
}

extern "C" void kernel_launch(void* const* d_in, const int* in_sizes, int n_in,
                              void* d_out, int out_size, void* d_ws, size_t ws_size,
                              hipStream_t stream) {
    const float* centers = (const float*)d_in[0];   // [B,N,3] f32
    const float* mri     = (const float*)d_in[1];   // [4,4]
    const float* aal     = (const float*)d_in[2];   // [4,4]
    const float* vol     = (const float*)d_in[3];   // [D,H,W]
    const float* table   = (const float*)d_in[4];   // [117,768]
    float* out = (float*)d_out;
    float* M   = (float*)d_ws;                      // 12 floats

    int P = in_sizes[0] / 3;                        // 65536

    compute_M_kernel<<<1, 64, 0, stream>>>(mri, aal, M);

    // 4 waves/block, 2 points/wave -> 8 points per block
    int blocks = (P + 7) / 8;
    aal_embed_kernel<<<blocks, 256, 0, stream>>>(centers, M, vol, table, out, P);
}

// Round 4
// 223.572 us; speedup vs baseline: 1.0617x; 1.0617x over previous
//
#include <hip/hip_runtime.h>
#include <math.h>

#define REGION_MAX 116
#define EMB 768
#define EMB4 192          // EMB / 4 float4s per row
#define DIM_D 182
#define DIM_H 218
#define DIM_W 182

typedef float v4f __attribute__((ext_vector_type(4)));

// --- phase 1: region id per point -> d_ws (also computes M per-block in LDS) ---
__global__ __launch_bounds__(256) void region_kernel(
    const float* __restrict__ centers,   // [P,3]
    const float* __restrict__ mri,       // [4,4]
    const float* __restrict__ aal,       // [4,4]
    const float* __restrict__ vol,       // [D,H,W]
    int* __restrict__ rid_out,           // [P]
    int P) {
    __shared__ float M[12];
    if (threadIdx.x == 0) {
        // M = inv(aal) @ mri, top 3 rows. Gauss-Jordan w/ partial pivoting.
        float a[4][8];
        for (int i = 0; i < 4; ++i)
            for (int j = 0; j < 4; ++j) {
                a[i][j]     = aal[i * 4 + j];
                a[i][j + 4] = (i == j) ? 1.0f : 0.0f;
            }
        for (int c = 0; c < 4; ++c) {
            int piv = c;
            float best = fabsf(a[c][c]);
            for (int r = c + 1; r < 4; ++r) {
                float v = fabsf(a[r][c]);
                if (v > best) { best = v; piv = r; }
            }
            if (piv != c)
                for (int j = 0; j < 8; ++j) {
                    float t = a[c][j]; a[c][j] = a[piv][j]; a[piv][j] = t;
                }
            float inv = 1.0f / a[c][c];
            for (int j = 0; j < 8; ++j) a[c][j] *= inv;
            for (int r = 0; r < 4; ++r) {
                if (r == c) continue;
                float f = a[r][c];
                for (int j = 0; j < 8; ++j) a[r][j] -= f * a[c][j];
            }
        }
        for (int i = 0; i < 3; ++i)
            for (int j = 0; j < 4; ++j) {
                float s = 0.0f;
                for (int k = 0; k < 4; ++k) s += a[i][4 + k] * mri[k * 4 + j];
                M[i * 4 + j] = s;
            }
    }
    __syncthreads();

    int p = blockIdx.x * blockDim.x + threadIdx.x;
    if (p >= P) return;

    float px = centers[p * 3 + 0];
    float py = centers[p * 3 + 1];
    float pz = centers[p * 3 + 2];

    float fx = M[0] * px + M[1] * py + M[2]  * pz + M[3];
    float fy = M[4] * px + M[5] * py + M[6]  * pz + M[7];
    float fz = M[8] * px + M[9] * py + M[10] * pz + M[11];

    int x = (int)rintf(fx);   // round half-to-even, matches jnp.round
    int y = (int)rintf(fy);
    int z = (int)rintf(fz);

    bool inb = (x >= 0) & (x < DIM_D) & (y >= 0) & (y < DIM_H) &
               (z >= 0) & (z < DIM_W);
    int cx = min(max(x, 0), DIM_D - 1);
    int cy = min(max(y, 0), DIM_H - 1);
    int cz = min(max(z, 0), DIM_W - 1);

    int region = (int)vol[((size_t)cx * DIM_H + cy) * DIM_W + cz];  // trunc = astype(int32)
    rid_out[p] = (inb && region >= 0 && region <= REGION_MAX) ? region : 0;
}

// --- phase 2: flat streaming gather-copy, one thread per output float4 ---
__global__ __launch_bounds__(256) void copy_kernel(
    const int* __restrict__ rid,         // [P]
    const float* __restrict__ table,     // [117, EMB]
    float* __restrict__ out,             // [P, EMB]
    long total4) {                       // P * EMB4
    long i = (long)blockIdx.x * blockDim.x + threadIdx.x;
    if (i >= total4) return;
    long p = i / EMB4;                   // magic-mul div by 192
    int  c = (int)(i - p * EMB4);
    int  r = rid[p];                     // L1/L2 hit, shared by 192 threads
    const v4f* __restrict__ src = (const v4f*)(table) + (long)r * EMB4 + c;
    v4f v = *src;                        // table resident in L2 (359 KB)
    __builtin_nontemporal_store(v, ((v4f*)out) + i);
}

extern "C" void kernel_launch(void* const* d_in, const int* in_sizes, int n_in,
                              void* d_out, int out_size, void* d_ws, size_t ws_size,
                              hipStream_t stream) {
    const float* centers = (const float*)d_in[0];   // [B,N,3] f32
    const float* mri     = (const float*)d_in[1];   // [4,4]
    const float* aal     = (const float*)d_in[2];   // [4,4]
    const float* vol     = (const float*)d_in[3];   // [D,H,W]
    const float* table   = (const float*)d_in[4];   // [117,768]
    float* out = (float*)d_out;
    int*   rid = (int*)d_ws;                        // [P] ints

    int P = in_sizes[0] / 3;                        // 65536

    int blocks1 = (P + 255) / 256;
    region_kernel<<<blocks1, 256, 0, stream>>>(centers, mri, aal, vol, rid, P);

    long total4 = (long)P * EMB4;                   // 12,582,912
    int blocks2 = (int)((total4 + 255) / 256);
    copy_kernel<<<blocks2, 256, 0, stream>>>(rid, table, out, total4);
}